// Round 1
// baseline (777.050 us; speedup 1.0000x reference)
//
#include <hip/hip_runtime.h>
#include <math.h>

#define N_NODES 50000
#define N_EDGES 600000
#define HID 128
#define N_GRAPHS 64
#define BCAP 32        // bucket capacity; overflow folded into agg rare path
#define OVF_CAP 4096
#define PCHUNK 8
#define LDSP 136       // padded LDS row stride (bf16): 272B = 17*16B -> bank-rotates A-frag reads

typedef __attribute__((ext_vector_type(8))) short short8;
typedef __attribute__((ext_vector_type(4))) float floatx4;

__device__ __forceinline__ float softplus_f(float v) {
    return fmaxf(v, 0.0f) + __logf(1.0f + __expf(-fabsf(v)));
}
__device__ __forceinline__ unsigned short f2bf(float f) {
    unsigned u = __float_as_uint(f);
    u = (u + 0x7FFFu + ((u >> 16) & 1u)) >> 16;   // RNE; inputs finite
    return (unsigned short)u;
}
__device__ __forceinline__ float bflo(unsigned u) { return __uint_as_float(u << 16); }
__device__ __forceinline__ float bfhi(unsigned u) { return __uint_as_float(u & 0xFFFF0000u); }

// ---- f32 -> bf16 row-major pack (node_attr) ----
__global__ void pack_x(const float* __restrict__ xf, unsigned short* __restrict__ xb, int nelem4) {
    int t = blockIdx.x * 256 + threadIdx.x;
    if (t >= nelem4) return;
    float4 v = *(const float4*)(xf + (size_t)t * 4);
    unsigned o0 = (unsigned)f2bf(v.x) | ((unsigned)f2bf(v.y) << 16);
    unsigned o1 = (unsigned)f2bf(v.z) | ((unsigned)f2bf(v.w) << 16);
    *(uint2*)(xb + (size_t)t * 4) = make_uint2(o0, o1);
}

// ---- bucket build: slot = atomicAdd(cnt[dst]); overflow keeps (e,src,dst) ----
__global__ void build_buckets(const int* __restrict__ ei, int* __restrict__ cnt,
                              int2* __restrict__ bkt, int4* __restrict__ ovf) {
    int e = blockIdx.x * 256 + threadIdx.x;
    if (e >= N_EDGES) return;
    int src = ei[e];
    int dst = ei[N_EDGES + e];
    int slot = atomicAdd(&cnt[dst], 1);
    if (slot < BCAP) {
        bkt[(size_t)dst * BCAP + slot] = make_int2(e, src);
    } else {
        int k = atomicAdd(&cnt[N_NODES], 1);
        if (k < OVF_CAP) ovf[k] = make_int4(e, src, dst, 0);
    }
}

// ---- aggregation helpers (quarter-wave per edge: 16 lanes x 8 feats) ----
__device__ __forceinline__ void acc8_bf(float* acc, uint4 ev, uint4 xv) {
    acc[0] += softplus_f(bflo(ev.x) + bflo(xv.x));
    acc[1] += softplus_f(bfhi(ev.x) + bfhi(xv.x));
    acc[2] += softplus_f(bflo(ev.y) + bflo(xv.y));
    acc[3] += softplus_f(bfhi(ev.y) + bfhi(xv.y));
    acc[4] += softplus_f(bflo(ev.z) + bflo(xv.z));
    acc[5] += softplus_f(bfhi(ev.z) + bfhi(xv.z));
    acc[6] += softplus_f(bflo(ev.w) + bflo(xv.w));
    acc[7] += softplus_f(bfhi(ev.w) + bfhi(xv.w));
}
__device__ __forceinline__ void acc8_f32(float* acc, float4 e0, float4 e1, uint4 xv) {
    acc[0] += softplus_f(e0.x + bflo(xv.x));
    acc[1] += softplus_f(e0.y + bfhi(xv.x));
    acc[2] += softplus_f(e0.z + bflo(xv.y));
    acc[3] += softplus_f(e0.w + bfhi(xv.y));
    acc[4] += softplus_f(e1.x + bflo(xv.z));
    acc[5] += softplus_f(e1.y + bfhi(xv.z));
    acc[6] += softplus_f(e1.z + bflo(xv.w));
    acc[7] += softplus_f(e1.w + bfhi(xv.w));
}
__device__ __forceinline__ void store_bf8(unsigned short* __restrict__ eb, int e, int l,
                                          float4 e0, float4 e1) {
    uint4 st;
    st.x = (unsigned)f2bf(e0.x) | ((unsigned)f2bf(e0.y) << 16);
    st.y = (unsigned)f2bf(e0.z) | ((unsigned)f2bf(e0.w) << 16);
    st.z = (unsigned)f2bf(e1.x) | ((unsigned)f2bf(e1.y) << 16);
    st.w = (unsigned)f2bf(e1.z) | ((unsigned)f2bf(e1.w) << 16);
    *(uint4*)(eb + (size_t)e * HID + l * 8) = st;
}

// ---- aggregation: wave/node, QUARTER-wave/edge (4 edges in flight, x2 unroll) ----
// L0=1: edge_attr read f32, bf16 copy written to eb.  L0=0: edge_attr read bf16 from eb.
// outb[n] = bf16( x[n] + sum_e softplus(edge_attr[e] + x[src_e]) )
template<int L0>
__global__ void __launch_bounds__(256) agg_kernel_t(const unsigned short* __restrict__ xb,
        const float* __restrict__ ef, unsigned short* __restrict__ eb,
        const int* __restrict__ cnt, const int2* __restrict__ bkt,
        const int4* __restrict__ ovf, unsigned short* __restrict__ outb) {
    int wave = blockIdx.x * 4 + (threadIdx.x >> 6);
    int lane = threadIdx.x & 63;
    int n = __builtin_amdgcn_readfirstlane(wave);
    if (n >= N_NODES) return;
    int q = lane >> 4;          // which edge of a 4-group this quarter handles
    int l = lane & 15;          // 8-feat segment index within the 128-feat row
    int ctot = cnt[n];
    int c = ctot < BCAP ? ctot : BCAP;
    const int2* bk = bkt + (size_t)n * BCAP;
    float acc[8];
    #pragma unroll
    for (int j = 0; j < 8; j++) acc[j] = 0.f;
    int s = 0;
    for (; s + 8 <= c; s += 8) {
        int2 pA = bk[s + q];
        int2 pB = bk[s + 4 + q];
        if (L0) {
            float4 a0 = *(const float4*)(ef + (size_t)pA.x * HID + l * 8);
            float4 a1 = *(const float4*)(ef + (size_t)pA.x * HID + l * 8 + 4);
            uint4  xa = *(const uint4*)(xb + (size_t)pA.y * HID + l * 8);
            float4 b0 = *(const float4*)(ef + (size_t)pB.x * HID + l * 8);
            float4 b1 = *(const float4*)(ef + (size_t)pB.x * HID + l * 8 + 4);
            uint4  xv = *(const uint4*)(xb + (size_t)pB.y * HID + l * 8);
            store_bf8(eb, pA.x, l, a0, a1);
            store_bf8(eb, pB.x, l, b0, b1);
            acc8_f32(acc, a0, a1, xa);
            acc8_f32(acc, b0, b1, xv);
        } else {
            uint4 ea = *(const uint4*)(eb + (size_t)pA.x * HID + l * 8);
            uint4 xa = *(const uint4*)(xb + (size_t)pA.y * HID + l * 8);
            uint4 ec = *(const uint4*)(eb + (size_t)pB.x * HID + l * 8);
            uint4 xv = *(const uint4*)(xb + (size_t)pB.y * HID + l * 8);
            acc8_bf(acc, ea, xa);
            acc8_bf(acc, ec, xv);
        }
    }
    for (; s < c; s += 4) {
        if (s + q < c) {
            int2 p = bk[s + q];
            if (L0) {
                float4 e0 = *(const float4*)(ef + (size_t)p.x * HID + l * 8);
                float4 e1 = *(const float4*)(ef + (size_t)p.x * HID + l * 8 + 4);
                uint4  xv = *(const uint4*)(xb + (size_t)p.y * HID + l * 8);
                store_bf8(eb, p.x, l, e0, e1);
                acc8_f32(acc, e0, e1, xv);
            } else {
                uint4 ev = *(const uint4*)(eb + (size_t)p.x * HID + l * 8);
                uint4 xv = *(const uint4*)(xb + (size_t)p.y * HID + l * 8);
                acc8_bf(acc, ev, xv);
            }
        }
    }
    if (ctot > BCAP) {          // rare: scan overflow list for this dst
        int k = cnt[N_NODES]; if (k > OVF_CAP) k = OVF_CAP;
        for (int i = 0; i < k; i++) {
            int4 t = ovf[i];
            if (t.z == n && q == 0) {
                if (L0) {
                    float4 e0 = *(const float4*)(ef + (size_t)t.x * HID + l * 8);
                    float4 e1 = *(const float4*)(ef + (size_t)t.x * HID + l * 8 + 4);
                    uint4  xv = *(const uint4*)(xb + (size_t)t.y * HID + l * 8);
                    store_bf8(eb, t.x, l, e0, e1);
                    acc8_f32(acc, e0, e1, xv);
                } else {
                    uint4 ev = *(const uint4*)(eb + (size_t)t.x * HID + l * 8);
                    uint4 xv = *(const uint4*)(xb + (size_t)t.y * HID + l * 8);
                    acc8_bf(acc, ev, xv);
                }
            }
        }
    }
    // reduce 4 quarters -> quarter 0
    #pragma unroll
    for (int j = 0; j < 8; j++) {
        acc[j] += __shfl_xor(acc[j], 16);
        acc[j] += __shfl_xor(acc[j], 32);
    }
    if (q == 0) {
        uint4 xn = *(const uint4*)(xb + (size_t)n * HID + l * 8);
        acc[0] += bflo(xn.x); acc[1] += bfhi(xn.x);
        acc[2] += bflo(xn.y); acc[3] += bfhi(xn.y);
        acc[4] += bflo(xn.z); acc[5] += bfhi(xn.z);
        acc[6] += bflo(xn.w); acc[7] += bfhi(xn.w);
        uint4 o;
        o.x = (unsigned)f2bf(acc[0]) | ((unsigned)f2bf(acc[1]) << 16);
        o.y = (unsigned)f2bf(acc[2]) | ((unsigned)f2bf(acc[3]) << 16);
        o.z = (unsigned)f2bf(acc[4]) | ((unsigned)f2bf(acc[5]) << 16);
        o.w = (unsigned)f2bf(acc[6]) | ((unsigned)f2bf(acc[7]) << 16);
        *(uint4*)(outb + (size_t)n * HID + l * 8) = o;
    }
}

// ---- pack W[n][k] (f32) into MFMA B-frag layout (bf16) ----
__global__ void pack_w(const float* __restrict__ W1, const float* __restrict__ W2,
                       unsigned short* __restrict__ pw) {
    int t = blockIdx.x * 256 + threadIdx.x;
    if (t >= 6 * 32 * 64) return;
    int lane = t & 63;
    int tile = (t >> 6) & 31;
    int mat = t >> 11;                       // 0..5 = layer*2 + which
    int kt = tile >> 3, nt = tile & 7;
    const float* W = (mat & 1) ? W2 : W1;
    W += (size_t)(mat >> 1) * HID * HID;
    int n = nt * 16 + (lane & 15);
    int kbase = kt * 32 + (lane >> 4) * 8;
    short8 v;
    #pragma unroll
    for (int j = 0; j < 8; j++) v[j] = (short)f2bf(W[(size_t)n * HID + kbase + j]);
    *((short8*)(pw + (size_t)t * 8)) = v;
}

// ---- fused MLP: out = [softplus]( softplus(A@W1^T+b1) @ W2^T + b2 ) ----
// block = 4 waves: 2 row-tiles x 2 col-halves; h round-trips via LDS (bf16).
__global__ void __launch_bounds__(256) mlp_fused(const unsigned short* __restrict__ A,
        const unsigned short* __restrict__ pw1, const unsigned short* __restrict__ pw2,
        const float* __restrict__ b1, const float* __restrict__ b2,
        void* __restrict__ outp, int final_layer) {
    __shared__ __align__(16) unsigned short hl[2][16][LDSP];
    int wave = threadIdx.x >> 6, lane = threadIdx.x & 63;
    int rt = wave >> 1, ch = wave & 1;
    int m = lane & 15, q = lane >> 4;
    int r0 = blockIdx.x * 32 + rt * 16;
    int row = r0 + m;
    bool rv = row < N_NODES;
    short8 zf = {0, 0, 0, 0, 0, 0, 0, 0};
    floatx4 zero = {0.f, 0.f, 0.f, 0.f};
    floatx4 acc[4];
    #pragma unroll
    for (int t = 0; t < 4; t++) acc[t] = zero;
    const short8* ar = (const short8*)(A + (size_t)row * HID + q * 8);
    const short8* w1 = (const short8*)pw1;
    #pragma unroll
    for (int kt = 0; kt < 4; kt++) {
        short8 af = rv ? ar[kt * 4] : zf;   // A[row][kt*32+q*8 ..+8], direct bf16
        const short8* wp = w1 + (size_t)(kt * 8 + ch * 4) * 64 + lane;
        #pragma unroll
        for (int t = 0; t < 4; t++)
            acc[t] = __builtin_amdgcn_mfma_f32_16x16x32_bf16(af, wp[t * 64], acc[t], 0, 0, 0);
    }
    // epilogue 1: h = softplus(acc + b1) -> bf16 -> LDS (C-layout -> A-layout)
    #pragma unroll
    for (int t = 0; t < 4; t++) {
        int col = ch * 64 + t * 16 + m;
        float bb = b1[col];
        #pragma unroll
        for (int i = 0; i < 4; i++)
            hl[rt][q * 4 + i][col] = f2bf(softplus_f(acc[t][i] + bb));
    }
    __syncthreads();
    #pragma unroll
    for (int t = 0; t < 4; t++) acc[t] = zero;
    const short8* w2 = (const short8*)pw2;
    #pragma unroll
    for (int kt = 0; kt < 4; kt++) {
        short8 af = *(const short8*)&hl[rt][m][kt * 32 + q * 8];
        const short8* wp = w2 + (size_t)(kt * 8 + ch * 4) * 64 + lane;
        #pragma unroll
        for (int t = 0; t < 4; t++)
            acc[t] = __builtin_amdgcn_mfma_f32_16x16x32_bf16(af, wp[t * 64], acc[t], 0, 0, 0);
    }
    if (final_layer) {
        float* out = (float*)outp;
        #pragma unroll
        for (int t = 0; t < 4; t++) {
            int col = ch * 64 + t * 16 + m;
            float bb = b2[col];
            #pragma unroll
            for (int i = 0; i < 4; i++) {
                int r = r0 + q * 4 + i;
                if (r < N_NODES) out[(size_t)r * HID + col] = acc[t][i] + bb;
            }
        }
    } else {
        __syncthreads();    // all GEMM2 LDS reads done before overwrite
        #pragma unroll
        for (int t = 0; t < 4; t++) {
            int col = ch * 64 + t * 16 + m;
            float bb = b2[col];
            #pragma unroll
            for (int i = 0; i < 4; i++)
                hl[rt][q * 4 + i][col] = f2bf(softplus_f(acc[t][i] + bb));
        }
        __syncthreads();
        // coalesced copy-out: thread -> (row = tid>>3, 16-col segment)
        unsigned short* outb = (unsigned short*)outp;
        int tid = threadIdx.x;
        int orow = tid >> 3, cseg = (tid & 7) * 16;
        int gr = blockIdx.x * 32 + orow;
        if (gr < N_NODES) {
            uint4 v0 = *(const uint4*)&hl[orow >> 4][orow & 15][cseg];
            uint4 v1 = *(const uint4*)&hl[orow >> 4][orow & 15][cseg + 8];
            *(uint4*)(outb + (size_t)gr * HID + cseg) = v0;
            *(uint4*)(outb + (size_t)gr * HID + cseg + 8) = v1;
        }
    }
}

// ---- pool: sorted batch -> boundaries -> chunked partials -> reduce ----
__global__ void find_bounds(const int* __restrict__ batch, int* __restrict__ start) {
    int n = blockIdx.x * 256 + threadIdx.x;
    if (n >= N_NODES) return;
    int bn = batch[n];
    int bp = (n == 0) ? -1 : batch[n - 1];
    for (int g = bp + 1; g <= bn; g++) start[g] = n;
    if (n == N_NODES - 1)
        for (int g = bn + 1; g <= N_GRAPHS; g++) start[g] = N_NODES;
}

__global__ void pool_partial(const float* __restrict__ nf, const int* __restrict__ start,
                             float* __restrict__ part) {
    int g = blockIdx.x >> 3, c = blockIdx.x & (PCHUNK - 1);
    int j = threadIdx.x;
    int s = start[g], e = start[g + 1];
    int len = e - s;
    int b0 = s + (len * c) / PCHUNK;
    int b1 = s + (len * (c + 1)) / PCHUNK;
    float acc = 0.f;
    for (int n = b0; n < b1; n++) acc += nf[(size_t)n * HID + j];
    part[(size_t)blockIdx.x * HID + j] = acc;
}

__global__ void pool_final(const float* __restrict__ part, float* __restrict__ gout) {
    int g = blockIdx.x, j = threadIdx.x;
    float acc = 0.f;
    #pragma unroll
    for (int c = 0; c < PCHUNK; c++) acc += part[(size_t)(g * PCHUNK + c) * HID + j];
    gout[(size_t)g * HID + j] = acc;
}

extern "C" void kernel_launch(void* const* d_in, const int* in_sizes, int n_in,
                              void* d_out, int out_size, void* d_ws, size_t ws_size,
                              hipStream_t stream) {
    const float* node_attr = (const float*)d_in[0];
    const float* edge_attr = (const float*)d_in[1];
    const int*   ei        = (const int*)d_in[2];
    const int*   batch     = (const int*)d_in[3];
    const float* W1        = (const float*)d_in[4];
    const float* B1        = (const float*)d_in[5];
    const float* W2        = (const float*)d_in[6];
    const float* B2        = (const float*)d_in[7];

    float* gout    = (float*)d_out;                    // [64,128]
    float* nodeout = (float*)d_out + N_GRAPHS * HID;   // [50000,128]

    const size_t NH = (size_t)N_NODES * HID;
    unsigned short* nab  = (unsigned short*)d_ws;      // bf16 node_attr
    unsigned short* bufA = nab + NH;                   // bf16 agg out (MLP A)
    unsigned short* bufB = bufA + NH;                  // bf16 x between layers
    int*   cnt = (int*)(bufB + NH);                    // 50001 (+pad)
    int4*  ovf = (int4*)(cnt + 50004);                 // OVF_CAP (16B aligned)
    int2*  bkt = (int2*)(ovf + OVF_CAP);               // 50000*BCAP
    unsigned short* pw = (unsigned short*)(bkt + (size_t)N_NODES * BCAP);  // 6*16384
    int*   startb = (int*)(pw + 6 * 16384);            // 65 (+pad)
    float* part = (float*)(startb + 68);               // 64*PCHUNK*128
    unsigned short* eb = (unsigned short*)(part + (size_t)N_GRAPHS * PCHUNK * HID); // bf16 edge_attr [600000,128]

    hipMemsetAsync(cnt, 0, (size_t)50001 * sizeof(int), stream);
    build_buckets<<<(N_EDGES + 255) / 256, 256, 0, stream>>>(ei, cnt, bkt, ovf);
    pack_w<<<(6 * 32 * 64 + 255) / 256, 256, 0, stream>>>(W1, W2, pw);
    pack_x<<<((int)(NH / 4) + 255) / 256, 256, 0, stream>>>(node_attr, nab, (int)(NH / 4));
    find_bounds<<<(N_NODES + 255) / 256, 256, 0, stream>>>(batch, startb);

    const int agg_blocks = (N_NODES + 3) / 4;
    const int mlp_blocks = (N_NODES + 31) / 32;

    const unsigned short* xcur = nab;
    for (int i = 0; i < 3; i++) {
        if (i == 0)
            agg_kernel_t<1><<<agg_blocks, 256, 0, stream>>>(xcur, edge_attr, eb, cnt, bkt, ovf, bufA);
        else
            agg_kernel_t<0><<<agg_blocks, 256, 0, stream>>>(xcur, edge_attr, eb, cnt, bkt, ovf, bufA);
        void* outp = (i == 2) ? (void*)nodeout : (void*)bufB;
        mlp_fused<<<mlp_blocks, 256, 0, stream>>>(bufA,
                pw + (size_t)(i * 2) * 16384, pw + (size_t)(i * 2 + 1) * 16384,
                B1 + (size_t)i * HID, B2 + (size_t)i * HID, outp, (i == 2) ? 1 : 0);
        xcur = bufB;
    }
    pool_partial<<<N_GRAPHS * PCHUNK, HID, 0, stream>>>(nodeout, startb, part);
    pool_final<<<N_GRAPHS, HID, 0, stream>>>(part, gout);
}